// Round 5
// baseline (907.756 us; speedup 1.0000x reference)
//
#include <hip/hip_runtime.h>
#include <hip/hip_bf16.h>

typedef __attribute__((ext_vector_type(8))) __bf16 bf16x8;
typedef __attribute__((ext_vector_type(4))) __bf16 bf16x4;
typedef __attribute__((ext_vector_type(4))) float f32x4;

#define AS1(p) ((__attribute__((address_space(1))) void*)(p))
#define AS3(p) ((__attribute__((address_space(3))) void*)(p))

// ---------------------------------------------------------------- f32 -> bf16
__global__ void f2b_kernel(const float4* __restrict__ in, bf16x4* __restrict__ out, int n4) {
    int idx = blockIdx.x * blockDim.x + threadIdx.x;
    int stride = gridDim.x * blockDim.x;
    for (int i = idx; i < n4; i += stride) {
        float4 v = in[i];
        bf16x4 o;
        o[0] = (__bf16)v.x; o[1] = (__bf16)v.y; o[2] = (__bf16)v.z; o[3] = (__bf16)v.w;
        out[i] = o;
    }
}

// ---------------------------------------------------------------- 256x256 pipelined GEMM
// C = A @ B^T. 512 thr = 8 waves (2M x 4N), per-wave 128x64 output, acc[8][4].
// K in 32-wide slots; 4-slot LDS ring staged 3 ahead (counted vmcnt, 1 barrier/slot).
// MODE 0: qkv out bf16 + fused per-head RMSNorm (q scaled by Dh^-0.5 * log2e for exp2 softmax).
// MODE 1: f32 out + bias.
template<int MODE>
__global__ __launch_bounds__(512, 2)
void gemm256(const __bf16* __restrict__ A, const __bf16* __restrict__ Bw,
             const float* __restrict__ bias, const float* __restrict__ qw,
             const float* __restrict__ kw, float* __restrict__ Cf,
             __bf16* __restrict__ Cb, int M, int N, int K, int nbn)
{
    __shared__ __bf16 Asl[4][256 * 32];
    __shared__ __bf16 Bsl[4][256 * 32];
    const int tid = threadIdx.x, l = tid & 63, w = tid >> 6;
    const int fr = l & 15, fk = l >> 4;

    const int cpx = gridDim.x >> 3;
    const int wg = (blockIdx.x & 7) * cpx + (blockIdx.x >> 3);
    const int bm = wg / nbn, bn = wg % nbn;

    const __bf16* Ag = A + (size_t)bm * 256 * K;
    const __bf16* Bg = Bw + (size_t)bn * 256 * K;

    const int arow = tid >> 2;
    const int uch = (tid & 3) ^ (arow & 3);
    const size_t ga = (size_t)arow * K + uch * 8;
    const size_t ga2 = ga + (size_t)128 * K;

    const int axc = (fk ^ (fr & 3)) * 16;
    int aoff[8], boff[4];
    #pragma unroll
    for (int m = 0; m < 8; ++m)
        aoff[m] = ((w >> 2) * 128 + m * 16 + fr) * 64 + axc;
    #pragma unroll
    for (int n = 0; n < 4; ++n)
        boff[n] = ((w & 3) * 64 + n * 16 + fr) * 64 + axc;

    f32x4 acc[8][4] = {};

#define STAGE256(S) do {                                                                    \
    const int sb_ = (S) & 3;                                                                \
    __builtin_amdgcn_global_load_lds(AS1(Ag + (size_t)(S) * 32 + ga),                       \
        AS3((char*)&Asl[sb_][0] + tid * 16), 16, 0, 0);                                     \
    __builtin_amdgcn_global_load_lds(AS1(Ag + (size_t)(S) * 32 + ga2),                      \
        AS3((char*)&Asl[sb_][0] + tid * 16 + 8192), 16, 0, 0);                              \
    __builtin_amdgcn_global_load_lds(AS1(Bg + (size_t)(S) * 32 + ga),                       \
        AS3((char*)&Bsl[sb_][0] + tid * 16), 16, 0, 0);                                     \
    __builtin_amdgcn_global_load_lds(AS1(Bg + (size_t)(S) * 32 + ga2),                      \
        AS3((char*)&Bsl[sb_][0] + tid * 16 + 8192), 16, 0, 0);                              \
} while (0)

#define PHASE256(S, VMSTR, DOSTAGE) do {                                                    \
    asm volatile("s_waitcnt vmcnt(" VMSTR ")" ::: "memory");                                \
    __builtin_amdgcn_s_barrier();                                                           \
    __builtin_amdgcn_sched_barrier(0);                                                      \
    const int pb_ = (S) & 3;                                                                \
    bf16x8 af[8], bfv[4];                                                                   \
    _Pragma("unroll")                                                                       \
    for (int m = 0; m < 8; ++m)                                                             \
        af[m] = *(const bf16x8*)((const char*)&Asl[pb_][0] + aoff[m]);                      \
    _Pragma("unroll")                                                                       \
    for (int n = 0; n < 4; ++n)                                                             \
        bfv[n] = *(const bf16x8*)((const char*)&Bsl[pb_][0] + boff[n]);                     \
    if (DOSTAGE) STAGE256((S) + 3);                                                         \
    __builtin_amdgcn_s_setprio(1);                                                          \
    _Pragma("unroll")                                                                       \
    for (int m = 0; m < 8; ++m)                                                             \
        _Pragma("unroll")                                                                   \
        for (int n = 0; n < 4; ++n)                                                         \
            acc[m][n] = __builtin_amdgcn_mfma_f32_16x16x32_bf16(af[m], bfv[n], acc[m][n], 0, 0, 0); \
    __builtin_amdgcn_s_setprio(0);                                                          \
} while (0)

    const int S = K >> 5;
    STAGE256(0); STAGE256(1); STAGE256(2);
    for (int s = 0; s < S - 2; ++s)
        PHASE256(s, "8", (s + 3 < S));
    PHASE256(S - 2, "4", false);
    PHASE256(S - 1, "0", false);
#undef PHASE256
#undef STAGE256

    // ---------------- epilogue: C/D layout col = fr, row = fk*4 + r
    const int rb0 = bm * 256 + (w >> 2) * 128 + fk * 4;
    const int cb0 = bn * 256 + (w & 3) * 64;

    if (MODE == 1) {
        #pragma unroll
        for (int m = 0; m < 8; ++m)
            #pragma unroll
            for (int n = 0; n < 4; ++n) {
                const int col = cb0 + n * 16 + fr;
                const float bv = bias[col];
                #pragma unroll
                for (int r = 0; r < 4; ++r)
                    Cf[(size_t)(rb0 + m * 16 + r) * N + col] = acc[m][n][r] + bv;
            }
    } else {
        const int sect = bn >> 2;          // 0=q, 1=k, 2=v (nbn=12)
        float wn[4] = {1.f, 1.f, 1.f, 1.f};
        if (sect < 2) {
            const float* wp = (sect == 0) ? qw : kw;
            #pragma unroll
            for (int n = 0; n < 4; ++n) wn[n] = wp[n * 16 + fr];
        }
        #pragma unroll
        for (int m = 0; m < 8; ++m) {
            if (sect < 2) {
                float sc[4];
                #pragma unroll
                for (int r = 0; r < 4; ++r) {
                    float ps = 0.f;
                    #pragma unroll
                    for (int n = 0; n < 4; ++n) ps += acc[m][n][r] * acc[m][n][r];
                    ps += __shfl_xor(ps, 1); ps += __shfl_xor(ps, 2);
                    ps += __shfl_xor(ps, 4); ps += __shfl_xor(ps, 8);
                    sc[r] = rsqrtf(ps * (1.0f / 64.0f) + 1e-6f);
                    if (sect == 0) sc[r] *= 0.18033688011112042f;   // 0.125 * log2(e)
                }
                #pragma unroll
                for (int n = 0; n < 4; ++n)
                    #pragma unroll
                    for (int r = 0; r < 4; ++r)
                        Cb[(size_t)(rb0 + m * 16 + r) * N + cb0 + n * 16 + fr] =
                            (__bf16)(acc[m][n][r] * sc[r] * wn[n]);
            } else {
                #pragma unroll
                for (int n = 0; n < 4; ++n)
                    #pragma unroll
                    for (int r = 0; r < 4; ++r)
                        Cb[(size_t)(rb0 + m * 16 + r) * N + cb0 + n * 16 + fr] =
                            (__bf16)acc[m][n][r];
            }
        }
    }
}

// ---------------------------------------------------------------- V transpose: vt[b][h][d][n]
__global__ __launch_bounds__(256)
void vtrans_kernel(const __bf16* __restrict__ qkv, __bf16* __restrict__ vt)
{
    __shared__ __bf16 T[64][72];
    const int b = blockIdx.z, h = blockIdx.y, nb = blockIdx.x;
    const int t = threadIdx.x;
    {
        const int nl = t >> 2, q4 = t & 3;
        const __bf16* src = qkv + (size_t)(b * 1024 + nb * 64 + nl) * 3072 + 2048 + h * 64 + q4 * 16;
        bf16x8 v0 = *(const bf16x8*)src;
        bf16x8 v1 = *(const bf16x8*)(src + 8);
        *(bf16x8*)&T[nl][q4 * 16] = v0;
        *(bf16x8*)&T[nl][q4 * 16 + 8] = v1;
    }
    __syncthreads();
    {
        const int dl = t >> 2, nq = t & 3;
        bf16x8 o0, o1;
        #pragma unroll
        for (int i = 0; i < 8; ++i) { o0[i] = T[nq * 16 + i][dl]; o1[i] = T[nq * 16 + 8 + i][dl]; }
        __bf16* dst = vt + ((size_t)((b * 16 + h) * 64 + dl)) * 1024 + nb * 64 + nq * 16;
        *(bf16x8*)dst = o0;
        *(bf16x8*)(dst + 8) = o1;
    }
}

// ---------------------------------------------------------------- flash attention v4
// exp2-space softmax (log2e folded into q), defer-max (THR=11 in log2 units).
__global__ __launch_bounds__(256, 4)
void attn_kernel(const __bf16* __restrict__ qkv, const __bf16* __restrict__ vt,
                 __bf16* __restrict__ ao)
{
    __shared__ __bf16 Ks[2][64 * 64];
    __shared__ __bf16 Vs[2][64 * 64];
    __shared__ __bf16 Pl[4][16 * 64];
    const int tid = threadIdx.x, l = tid & 63, w = tid >> 6;
    const int fr = l & 15, fk = l >> 4;
    const int sw = (fr & 7) << 4;

    const int bi = blockIdx.x;
    const int L = (bi & 7) * 128 + (bi >> 3);
    const int qb = L & 3, h = (L >> 2) & 15, b = L >> 6;

    const __bf16* Kg = qkv + (size_t)b * 1024 * 3072 + 1024 + h * 64;
    const __bf16* Vg = vt + (size_t)((b * 16 + h) * 64) * 1024;
    const int srow = tid >> 3, scp = tid & 7;

#define STAGE(KT, BUF) do {                                                               \
    _Pragma("unroll")                                                                     \
    for (int i_ = 0; i_ < 2; ++i_) {                                                      \
        const int row_ = i_ * 32 + srow;                                                  \
        const int c_ = scp ^ (row_ & 7);                                                  \
        __builtin_amdgcn_global_load_lds(AS1(Kg + (size_t)((KT) * 64 + row_) * 3072 + c_ * 8), \
                                         AS3(&Ks[BUF][i_ * 2048 + tid * 8]), 16, 0, 0);   \
        __builtin_amdgcn_global_load_lds(AS1(Vg + (size_t)row_ * 1024 + (KT) * 64 + c_ * 8),   \
                                         AS3(&Vs[BUF][i_ * 2048 + tid * 8]), 16, 0, 0);   \
    } } while (0)

    STAGE(0, 0);

    const int qrow0 = b * 1024 + qb * 256 + w * 64;
    bf16x8 qf[4][2];
    #pragma unroll
    for (int qi = 0; qi < 4; ++qi)
        #pragma unroll
        for (int dc = 0; dc < 2; ++dc)
            qf[qi][dc] = *(const bf16x8*)&qkv[(size_t)(qrow0 + qi * 16 + fr) * 3072
                                              + h * 64 + dc * 32 + fk * 8];

    f32x4 oacc[4][4] = {};
    float m_r[4], ls[4];
    #pragma unroll
    for (int qi = 0; qi < 4; ++qi) { m_r[qi] = -1e30f; ls[qi] = 0.0f; }

    char* Pw = (char*)&Pl[w][0];
    __syncthreads();

    for (int kt = 0; kt < 16; ++kt) {
        const int cur = kt & 1;
        if (kt < 15) STAGE(kt + 1, cur ^ 1);

        bf16x8 kf[4][2], vf[4][2];
        #pragma unroll
        for (int n = 0; n < 4; ++n)
            #pragma unroll
            for (int dc = 0; dc < 2; ++dc)
                kf[n][dc] = *(const bf16x8*)&Ks[cur][(n * 16 + fr) * 64
                                                     + (((dc * 4 + fk) ^ (fr & 7)) * 8)];
        #pragma unroll
        for (int nd = 0; nd < 4; ++nd)
            #pragma unroll
            for (int kc = 0; kc < 2; ++kc)
                vf[nd][kc] = *(const bf16x8*)&Vs[cur][(nd * 16 + fr) * 64
                                                      + (((kc * 4 + fk) ^ (fr & 7)) * 8)];

        #pragma unroll
        for (int qi = 0; qi < 4; ++qi) {
            f32x4 sacc[4] = {};
            #pragma unroll
            for (int n = 0; n < 4; ++n)
                #pragma unroll
                for (int dc = 0; dc < 2; ++dc)
                    sacc[n] = __builtin_amdgcn_mfma_f32_16x16x32_bf16(kf[n][dc], qf[qi][dc],
                                                                      sacc[n], 0, 0, 0);

            float tm = -1e30f;
            #pragma unroll
            for (int n = 0; n < 4; ++n)
                #pragma unroll
                for (int r = 0; r < 4; ++r)
                    tm = fmaxf(tm, sacc[n][r]);
            tm = fmaxf(tm, __shfl_xor(tm, 16));
            tm = fmaxf(tm, __shfl_xor(tm, 32));

            // defer-max: rescale only when the running max grew by > 11 (log2 units)
            if (__any(tm > m_r[qi] + 11.0f)) {
                const float mnew = fmaxf(m_r[qi], tm);
                const float resc = exp2f(m_r[qi] - mnew);
                m_r[qi] = mnew;
                ls[qi] *= resc;
                float rb[4];
                #pragma unroll
                for (int r = 0; r < 4; ++r) rb[r] = __shfl(resc, (l & 48) + fk * 4 + r);
                #pragma unroll
                for (int nd = 0; nd < 4; ++nd)
                    #pragma unroll
                    for (int r = 0; r < 4; ++r) oacc[qi][nd][r] *= rb[r];
            }

            const float mcur = m_r[qi];
            float psum = 0.0f;
            #pragma unroll
            for (int n = 0; n < 4; ++n) {
                bf16x4 pk;
                #pragma unroll
                for (int r = 0; r < 4; ++r) {
                    float p = exp2f(sacc[n][r] - mcur);
                    psum += p;
                    pk[r] = (__bf16)p;
                }
                *(bf16x4*)(Pw + ((fr * 128 + n * 32 + fk * 8) ^ sw)) = pk;
            }
            psum += __shfl_xor(psum, 16);
            psum += __shfl_xor(psum, 32);
            ls[qi] += psum;

            bf16x8 pf[2];
            #pragma unroll
            for (int kc = 0; kc < 2; ++kc)
                pf[kc] = *(const bf16x8*)(Pw + ((fr * 128 + kc * 64 + fk * 16) ^ sw));
            #pragma unroll
            for (int nd = 0; nd < 4; ++nd)
                #pragma unroll
                for (int kc = 0; kc < 2; ++kc)
                    oacc[qi][nd] = __builtin_amdgcn_mfma_f32_16x16x32_bf16(pf[kc], vf[nd][kc],
                                                                           oacc[qi][nd], 0, 0, 0);
        }
        __syncthreads();
    }

    #pragma unroll
    for (int qi = 0; qi < 4; ++qi) {
        float inv[4];
        #pragma unroll
        for (int r = 0; r < 4; ++r)
            inv[r] = __builtin_amdgcn_rcpf(__shfl(ls[qi], (l & 48) + fk * 4 + r));
        #pragma unroll
        for (int nd = 0; nd < 4; ++nd)
            #pragma unroll
            for (int r = 0; r < 4; ++r)
                ao[(size_t)(qrow0 + qi * 16 + fk * 4 + r) * 1024 + h * 64 + nd * 16 + fr] =
                    (__bf16)(oacc[qi][nd][r] * inv[r]);
    }
#undef STAGE
}

// ---------------------------------------------------------------- launch
extern "C" void kernel_launch(void* const* d_in, const int* in_sizes, int n_in,
                              void* d_out, int out_size, void* d_ws, size_t ws_size,
                              hipStream_t stream)
{
    const float* x      = (const float*)d_in[0];
    const float* qkv_w  = (const float*)d_in[1];
    const float* proj_w = (const float*)d_in[2];
    const float* proj_b = (const float*)d_in[3];
    const float* qnw    = (const float*)d_in[4];
    const float* knw    = (const float*)d_in[5];

    char* ws = (char*)d_ws;
    __bf16* xb    = (__bf16*)(ws);                                 // 32 MB (reused as vt later)
    __bf16* wqkv  = (__bf16*)(ws + 33554432);                      // 6 MB
    __bf16* wproj = (__bf16*)(ws + 33554432 + 6291456);            // 2 MB
    __bf16* qkv   = (__bf16*)(ws + 41943040);                      // 96 MB
    __bf16* ao    = (__bf16*)(ws + 41943040 + 100663296);          // 32 MB
    __bf16* vt    = xb;                                            // xb dead after QKV GEMM

    f2b_kernel<<<2048, 256, 0, stream>>>((const float4*)x,      (bf16x4*)xb,    16777216 / 4);
    f2b_kernel<<<2048, 256, 0, stream>>>((const float4*)qkv_w,  (bf16x4*)wqkv,  3145728 / 4);
    f2b_kernel<<<1024, 256, 0, stream>>>((const float4*)proj_w, (bf16x4*)wproj, 1048576 / 4);

    gemm256<0><<<768, 512, 0, stream>>>(xb, wqkv, nullptr, qnw, knw,
                                        nullptr, qkv, 16384, 3072, 1024, 12);
    vtrans_kernel<<<dim3(16, 16, 16), 256, 0, stream>>>(qkv, vt);
    attn_kernel<<<1024, 256, 0, stream>>>(qkv, vt, ao);
    gemm256<1><<<256, 512, 0, stream>>>(ao, wproj, proj_b, nullptr, nullptr,
                                        (float*)d_out, nullptr, 16384, 1024, 1024, 4);
}

// Round 6
// 543.617 us; speedup vs baseline: 1.6698x; 1.6698x over previous
//
#include <hip/hip_runtime.h>
#include <hip/hip_bf16.h>

typedef __attribute__((ext_vector_type(8))) __bf16 bf16x8;
typedef __attribute__((ext_vector_type(4))) __bf16 bf16x4;
typedef __attribute__((ext_vector_type(4))) float f32x4;

#define AS1(p) ((__attribute__((address_space(1))) void*)(p))
#define AS3(p) ((__attribute__((address_space(3))) void*)(p))

// ---------------------------------------------------------------- f32 -> bf16
__global__ void f2b_kernel(const float4* __restrict__ in, bf16x4* __restrict__ out, int n4) {
    int idx = blockIdx.x * blockDim.x + threadIdx.x;
    int stride = gridDim.x * blockDim.x;
    for (int i = idx; i < n4; i += stride) {
        float4 v = in[i];
        bf16x4 o;
        o[0] = (__bf16)v.x; o[1] = (__bf16)v.y; o[2] = (__bf16)v.z; o[3] = (__bf16)v.w;
        out[i] = o;
    }
}

// ---------------------------------------------------------------- 256x256 pipelined GEMM
// C = A @ B^T. 512 thr = 8 waves (2M x 4N), per-wave 128x64 output, acc[8][4].
// K in 32-wide slots; 4-slot LDS ring staged 3 ahead (counted vmcnt, 1 barrier/slot).
// MODE 0: qkv out bf16 + fused per-head RMSNorm (q scaled by Dh^-0.5 * log2e for exp2 softmax).
// MODE 1: f32 out + bias.
template<int MODE>
__global__ __launch_bounds__(512, 2)
void gemm256(const __bf16* __restrict__ A, const __bf16* __restrict__ Bw,
             const float* __restrict__ bias, const float* __restrict__ qw,
             const float* __restrict__ kw, float* __restrict__ Cf,
             __bf16* __restrict__ Cb, int M, int N, int K, int nbn)
{
    __shared__ __bf16 Asl[4][256 * 32];
    __shared__ __bf16 Bsl[4][256 * 32];
    const int tid = threadIdx.x, l = tid & 63, w = tid >> 6;
    const int fr = l & 15, fk = l >> 4;

    const int cpx = gridDim.x >> 3;
    const int wg = (blockIdx.x & 7) * cpx + (blockIdx.x >> 3);
    const int bm = wg / nbn, bn = wg % nbn;

    const __bf16* Ag = A + (size_t)bm * 256 * K;
    const __bf16* Bg = Bw + (size_t)bn * 256 * K;

    const int arow = tid >> 2;
    const int uch = (tid & 3) ^ (arow & 3);
    const size_t ga = (size_t)arow * K + uch * 8;
    const size_t ga2 = ga + (size_t)128 * K;

    const int axc = (fk ^ (fr & 3)) * 16;
    int aoff[8], boff[4];
    #pragma unroll
    for (int m = 0; m < 8; ++m)
        aoff[m] = ((w >> 2) * 128 + m * 16 + fr) * 64 + axc;
    #pragma unroll
    for (int n = 0; n < 4; ++n)
        boff[n] = ((w & 3) * 64 + n * 16 + fr) * 64 + axc;

    f32x4 acc[8][4] = {};

#define STAGE256(S) do {                                                                    \
    const int sb_ = (S) & 3;                                                                \
    __builtin_amdgcn_global_load_lds(AS1(Ag + (size_t)(S) * 32 + ga),                       \
        AS3((char*)&Asl[sb_][0] + tid * 16), 16, 0, 0);                                     \
    __builtin_amdgcn_global_load_lds(AS1(Ag + (size_t)(S) * 32 + ga2),                      \
        AS3((char*)&Asl[sb_][0] + tid * 16 + 8192), 16, 0, 0);                              \
    __builtin_amdgcn_global_load_lds(AS1(Bg + (size_t)(S) * 32 + ga),                       \
        AS3((char*)&Bsl[sb_][0] + tid * 16), 16, 0, 0);                                     \
    __builtin_amdgcn_global_load_lds(AS1(Bg + (size_t)(S) * 32 + ga2),                      \
        AS3((char*)&Bsl[sb_][0] + tid * 16 + 8192), 16, 0, 0);                              \
} while (0)

#define PHASE256(S, VMSTR, DOSTAGE) do {                                                    \
    asm volatile("s_waitcnt vmcnt(" VMSTR ")" ::: "memory");                                \
    __builtin_amdgcn_s_barrier();                                                           \
    __builtin_amdgcn_sched_barrier(0);                                                      \
    const int pb_ = (S) & 3;                                                                \
    bf16x8 af[8], bfv[4];                                                                   \
    _Pragma("unroll")                                                                       \
    for (int m = 0; m < 8; ++m)                                                             \
        af[m] = *(const bf16x8*)((const char*)&Asl[pb_][0] + aoff[m]);                      \
    _Pragma("unroll")                                                                       \
    for (int n = 0; n < 4; ++n)                                                             \
        bfv[n] = *(const bf16x8*)((const char*)&Bsl[pb_][0] + boff[n]);                     \
    if (DOSTAGE) STAGE256((S) + 3);                                                         \
    __builtin_amdgcn_s_setprio(1);                                                          \
    _Pragma("unroll")                                                                       \
    for (int m = 0; m < 8; ++m)                                                             \
        _Pragma("unroll")                                                                   \
        for (int n = 0; n < 4; ++n)                                                         \
            acc[m][n] = __builtin_amdgcn_mfma_f32_16x16x32_bf16(af[m], bfv[n], acc[m][n], 0, 0, 0); \
    __builtin_amdgcn_s_setprio(0);                                                          \
} while (0)

    const int S = K >> 5;
    STAGE256(0); STAGE256(1); STAGE256(2);
    for (int s = 0; s < S - 2; ++s)
        PHASE256(s, "8", (s + 3 < S));
    PHASE256(S - 2, "4", false);
    PHASE256(S - 1, "0", false);
#undef PHASE256
#undef STAGE256

    // ---------------- epilogue: C/D layout col = fr, row = fk*4 + r
    const int rb0 = bm * 256 + (w >> 2) * 128 + fk * 4;
    const int cb0 = bn * 256 + (w & 3) * 64;

    if (MODE == 1) {
        #pragma unroll
        for (int m = 0; m < 8; ++m)
            #pragma unroll
            for (int n = 0; n < 4; ++n) {
                const int col = cb0 + n * 16 + fr;
                const float bv = bias[col];
                #pragma unroll
                for (int r = 0; r < 4; ++r)
                    Cf[(size_t)(rb0 + m * 16 + r) * N + col] = acc[m][n][r] + bv;
            }
    } else {
        const int sect = bn >> 2;          // 0=q, 1=k, 2=v (nbn=12)
        float wn[4] = {1.f, 1.f, 1.f, 1.f};
        if (sect < 2) {
            const float* wp = (sect == 0) ? qw : kw;
            #pragma unroll
            for (int n = 0; n < 4; ++n) wn[n] = wp[n * 16 + fr];
        }
        #pragma unroll
        for (int m = 0; m < 8; ++m) {
            if (sect < 2) {
                float sc[4];
                #pragma unroll
                for (int r = 0; r < 4; ++r) {
                    float ps = 0.f;
                    #pragma unroll
                    for (int n = 0; n < 4; ++n) ps += acc[m][n][r] * acc[m][n][r];
                    ps += __shfl_xor(ps, 1); ps += __shfl_xor(ps, 2);
                    ps += __shfl_xor(ps, 4); ps += __shfl_xor(ps, 8);
                    sc[r] = rsqrtf(ps * (1.0f / 64.0f) + 1e-6f);
                    if (sect == 0) sc[r] *= 0.18033688011112042f;   // 0.125 * log2(e)
                }
                #pragma unroll
                for (int n = 0; n < 4; ++n)
                    #pragma unroll
                    for (int r = 0; r < 4; ++r)
                        Cb[(size_t)(rb0 + m * 16 + r) * N + cb0 + n * 16 + fr] =
                            (__bf16)(acc[m][n][r] * sc[r] * wn[n]);
            } else {
                #pragma unroll
                for (int n = 0; n < 4; ++n)
                    #pragma unroll
                    for (int r = 0; r < 4; ++r)
                        Cb[(size_t)(rb0 + m * 16 + r) * N + cb0 + n * 16 + fr] =
                            (__bf16)acc[m][n][r];
            }
        }
    }
}

// ---------------------------------------------------------------- V transpose: vt[b][h][d][n]
__global__ __launch_bounds__(256)
void vtrans_kernel(const __bf16* __restrict__ qkv, __bf16* __restrict__ vt)
{
    __shared__ __bf16 T[64][72];
    const int b = blockIdx.z, h = blockIdx.y, nb = blockIdx.x;
    const int t = threadIdx.x;
    {
        const int nl = t >> 2, q4 = t & 3;
        const __bf16* src = qkv + (size_t)(b * 1024 + nb * 64 + nl) * 3072 + 2048 + h * 64 + q4 * 16;
        bf16x8 v0 = *(const bf16x8*)src;
        bf16x8 v1 = *(const bf16x8*)(src + 8);
        *(bf16x8*)&T[nl][q4 * 16] = v0;
        *(bf16x8*)&T[nl][q4 * 16 + 8] = v1;
    }
    __syncthreads();
    {
        const int dl = t >> 2, nq = t & 3;
        bf16x8 o0, o1;
        #pragma unroll
        for (int i = 0; i < 8; ++i) { o0[i] = T[nq * 16 + i][dl]; o1[i] = T[nq * 16 + 8 + i][dl]; }
        __bf16* dst = vt + ((size_t)((b * 16 + h) * 64 + dl)) * 1024 + nb * 64 + nq * 16;
        *(bf16x8*)dst = o0;
        *(bf16x8*)(dst + 8) = o1;
    }
}

// ---------------------------------------------------------------- flash attention v4b
// exp2-space softmax (log2e folded into q), defer-max (THR=11 in log2 units).
// launch_bounds(256,3): VGPR cap ~170 (need ~116, no spill), 3 blocks/CU.
__global__ __launch_bounds__(256, 3)
void attn_kernel(const __bf16* __restrict__ qkv, const __bf16* __restrict__ vt,
                 __bf16* __restrict__ ao)
{
    __shared__ __bf16 Ks[2][64 * 64];
    __shared__ __bf16 Vs[2][64 * 64];
    __shared__ __bf16 Pl[4][16 * 64];
    const int tid = threadIdx.x, l = tid & 63, w = tid >> 6;
    const int fr = l & 15, fk = l >> 4;
    const int sw = (fr & 7) << 4;

    const int bi = blockIdx.x;
    const int L = (bi & 7) * 128 + (bi >> 3);
    const int qb = L & 3, h = (L >> 2) & 15, b = L >> 6;

    const __bf16* Kg = qkv + (size_t)b * 1024 * 3072 + 1024 + h * 64;
    const __bf16* Vg = vt + (size_t)((b * 16 + h) * 64) * 1024;
    const int srow = tid >> 3, scp = tid & 7;

#define STAGE(KT, BUF) do {                                                               \
    _Pragma("unroll")                                                                     \
    for (int i_ = 0; i_ < 2; ++i_) {                                                      \
        const int row_ = i_ * 32 + srow;                                                  \
        const int c_ = scp ^ (row_ & 7);                                                  \
        __builtin_amdgcn_global_load_lds(AS1(Kg + (size_t)((KT) * 64 + row_) * 3072 + c_ * 8), \
                                         AS3(&Ks[BUF][i_ * 2048 + tid * 8]), 16, 0, 0);   \
        __builtin_amdgcn_global_load_lds(AS1(Vg + (size_t)row_ * 1024 + (KT) * 64 + c_ * 8),   \
                                         AS3(&Vs[BUF][i_ * 2048 + tid * 8]), 16, 0, 0);   \
    } } while (0)

    STAGE(0, 0);

    const int qrow0 = b * 1024 + qb * 256 + w * 64;
    bf16x8 qf[4][2];
    #pragma unroll
    for (int qi = 0; qi < 4; ++qi)
        #pragma unroll
        for (int dc = 0; dc < 2; ++dc)
            qf[qi][dc] = *(const bf16x8*)&qkv[(size_t)(qrow0 + qi * 16 + fr) * 3072
                                              + h * 64 + dc * 32 + fk * 8];

    f32x4 oacc[4][4] = {};
    float m_r[4], ls[4];
    #pragma unroll
    for (int qi = 0; qi < 4; ++qi) { m_r[qi] = -1e30f; ls[qi] = 0.0f; }

    char* Pw = (char*)&Pl[w][0];
    __syncthreads();

    for (int kt = 0; kt < 16; ++kt) {
        const int cur = kt & 1;
        if (kt < 15) STAGE(kt + 1, cur ^ 1);

        bf16x8 kf[4][2], vf[4][2];
        #pragma unroll
        for (int n = 0; n < 4; ++n)
            #pragma unroll
            for (int dc = 0; dc < 2; ++dc)
                kf[n][dc] = *(const bf16x8*)&Ks[cur][(n * 16 + fr) * 64
                                                     + (((dc * 4 + fk) ^ (fr & 7)) * 8)];
        #pragma unroll
        for (int nd = 0; nd < 4; ++nd)
            #pragma unroll
            for (int kc = 0; kc < 2; ++kc)
                vf[nd][kc] = *(const bf16x8*)&Vs[cur][(nd * 16 + fr) * 64
                                                      + (((kc * 4 + fk) ^ (fr & 7)) * 8)];

        #pragma unroll
        for (int qi = 0; qi < 4; ++qi) {
            f32x4 sacc[4] = {};
            #pragma unroll
            for (int n = 0; n < 4; ++n)
                #pragma unroll
                for (int dc = 0; dc < 2; ++dc)
                    sacc[n] = __builtin_amdgcn_mfma_f32_16x16x32_bf16(kf[n][dc], qf[qi][dc],
                                                                      sacc[n], 0, 0, 0);

            float tm = -1e30f;
            #pragma unroll
            for (int n = 0; n < 4; ++n)
                #pragma unroll
                for (int r = 0; r < 4; ++r)
                    tm = fmaxf(tm, sacc[n][r]);
            tm = fmaxf(tm, __shfl_xor(tm, 16));
            tm = fmaxf(tm, __shfl_xor(tm, 32));

            // defer-max: rescale only when the running max grew by > 11 (log2 units)
            if (__any(tm > m_r[qi] + 11.0f)) {
                const float mnew = fmaxf(m_r[qi], tm);
                const float resc = exp2f(m_r[qi] - mnew);
                m_r[qi] = mnew;
                ls[qi] *= resc;
                float rb[4];
                #pragma unroll
                for (int r = 0; r < 4; ++r) rb[r] = __shfl(resc, (l & 48) + fk * 4 + r);
                #pragma unroll
                for (int nd = 0; nd < 4; ++nd)
                    #pragma unroll
                    for (int r = 0; r < 4; ++r) oacc[qi][nd][r] *= rb[r];
            }

            const float mcur = m_r[qi];
            float psum = 0.0f;
            #pragma unroll
            for (int n = 0; n < 4; ++n) {
                bf16x4 pk;
                #pragma unroll
                for (int r = 0; r < 4; ++r) {
                    float p = exp2f(sacc[n][r] - mcur);
                    psum += p;
                    pk[r] = (__bf16)p;
                }
                *(bf16x4*)(Pw + ((fr * 128 + n * 32 + fk * 8) ^ sw)) = pk;
            }
            psum += __shfl_xor(psum, 16);
            psum += __shfl_xor(psum, 32);
            ls[qi] += psum;

            bf16x8 pf[2];
            #pragma unroll
            for (int kc = 0; kc < 2; ++kc)
                pf[kc] = *(const bf16x8*)(Pw + ((fr * 128 + kc * 64 + fk * 16) ^ sw));
            #pragma unroll
            for (int nd = 0; nd < 4; ++nd)
                #pragma unroll
                for (int kc = 0; kc < 2; ++kc)
                    oacc[qi][nd] = __builtin_amdgcn_mfma_f32_16x16x32_bf16(pf[kc], vf[nd][kc],
                                                                           oacc[qi][nd], 0, 0, 0);
        }
        __syncthreads();
    }

    #pragma unroll
    for (int qi = 0; qi < 4; ++qi) {
        float inv[4];
        #pragma unroll
        for (int r = 0; r < 4; ++r)
            inv[r] = __builtin_amdgcn_rcpf(__shfl(ls[qi], (l & 48) + fk * 4 + r));
        #pragma unroll
        for (int nd = 0; nd < 4; ++nd)
            #pragma unroll
            for (int r = 0; r < 4; ++r)
                ao[(size_t)(qrow0 + qi * 16 + fk * 4 + r) * 1024 + h * 64 + nd * 16 + fr] =
                    (__bf16)(oacc[qi][nd][r] * inv[r]);
    }
#undef STAGE
}

// ---------------------------------------------------------------- launch
extern "C" void kernel_launch(void* const* d_in, const int* in_sizes, int n_in,
                              void* d_out, int out_size, void* d_ws, size_t ws_size,
                              hipStream_t stream)
{
    const float* x      = (const float*)d_in[0];
    const float* qkv_w  = (const float*)d_in[1];
    const float* proj_w = (const float*)d_in[2];
    const float* proj_b = (const float*)d_in[3];
    const float* qnw    = (const float*)d_in[4];
    const float* knw    = (const float*)d_in[5];

    char* ws = (char*)d_ws;
    __bf16* xb    = (__bf16*)(ws);                                 // 32 MB (reused as vt later)
    __bf16* wqkv  = (__bf16*)(ws + 33554432);                      // 6 MB
    __bf16* wproj = (__bf16*)(ws + 33554432 + 6291456);            // 2 MB
    __bf16* qkv   = (__bf16*)(ws + 41943040);                      // 96 MB
    __bf16* ao    = (__bf16*)(ws + 41943040 + 100663296);          // 32 MB
    __bf16* vt    = xb;                                            // xb dead after QKV GEMM

    f2b_kernel<<<2048, 256, 0, stream>>>((const float4*)x,      (bf16x4*)xb,    16777216 / 4);
    f2b_kernel<<<2048, 256, 0, stream>>>((const float4*)qkv_w,  (bf16x4*)wqkv,  3145728 / 4);
    f2b_kernel<<<1024, 256, 0, stream>>>((const float4*)proj_w, (bf16x4*)wproj, 1048576 / 4);

    gemm256<0><<<768, 512, 0, stream>>>(xb, wqkv, nullptr, qnw, knw,
                                        nullptr, qkv, 16384, 3072, 1024, 12);
    vtrans_kernel<<<dim3(16, 16, 16), 256, 0, stream>>>(qkv, vt);
    attn_kernel<<<1024, 256, 0, stream>>>(qkv, vt, ao);
    gemm256<1><<<256, 512, 0, stream>>>(ao, wproj, proj_b, nullptr, nullptr,
                                        (float*)d_out, nullptr, 16384, 1024, 1024, 4);
}

// Round 7
// 308.986 us; speedup vs baseline: 2.9379x; 1.7594x over previous
//
#include <hip/hip_runtime.h>
#include <hip/hip_bf16.h>

typedef __attribute__((ext_vector_type(8))) __bf16 bf16x8;
typedef __attribute__((ext_vector_type(4))) __bf16 bf16x4;
typedef __attribute__((ext_vector_type(4))) float f32x4;

#define AS1(p) ((__attribute__((address_space(1))) void*)(p))
#define AS3(p) ((__attribute__((address_space(3))) void*)(p))

// ---------------------------------------------------------------- f32 -> bf16
__global__ void f2b_kernel(const float4* __restrict__ in, bf16x4* __restrict__ out, int n4) {
    int idx = blockIdx.x * blockDim.x + threadIdx.x;
    int stride = gridDim.x * blockDim.x;
    for (int i = idx; i < n4; i += stride) {
        float4 v = in[i];
        bf16x4 o;
        o[0] = (__bf16)v.x; o[1] = (__bf16)v.y; o[2] = (__bf16)v.z; o[3] = (__bf16)v.w;
        out[i] = o;
    }
}

// ---------------------------------------------------------------- 256x256 pipelined GEMM
// C = A @ B^T. 512 thr = 8 waves (2M x 4N), per-wave 128x64 output, acc[8][4].
// K in 32-wide slots; 4-slot LDS ring staged 3 ahead (counted vmcnt, 1 barrier/slot).
// MODE 0: qkv out bf16 + fused per-head RMSNorm (q scaled by Dh^-0.5 * log2e for exp2 softmax).
// MODE 1: f32 out + bias.
template<int MODE>
__global__ __launch_bounds__(512, 2)
void gemm256(const __bf16* __restrict__ A, const __bf16* __restrict__ Bw,
             const float* __restrict__ bias, const float* __restrict__ qw,
             const float* __restrict__ kw, float* __restrict__ Cf,
             __bf16* __restrict__ Cb, int M, int N, int K, int nbn)
{
    __shared__ __bf16 Asl[4][256 * 32];
    __shared__ __bf16 Bsl[4][256 * 32];
    const int tid = threadIdx.x, l = tid & 63, w = tid >> 6;
    const int fr = l & 15, fk = l >> 4;

    const int cpx = gridDim.x >> 3;
    const int wg = (blockIdx.x & 7) * cpx + (blockIdx.x >> 3);
    const int bm = wg / nbn, bn = wg % nbn;

    const __bf16* Ag = A + (size_t)bm * 256 * K;
    const __bf16* Bg = Bw + (size_t)bn * 256 * K;

    const int arow = tid >> 2;
    const int uch = (tid & 3) ^ (arow & 3);
    const size_t ga = (size_t)arow * K + uch * 8;
    const size_t ga2 = ga + (size_t)128 * K;

    const int axc = (fk ^ (fr & 3)) * 16;
    int aoff[8], boff[4];
    #pragma unroll
    for (int m = 0; m < 8; ++m)
        aoff[m] = ((w >> 2) * 128 + m * 16 + fr) * 64 + axc;
    #pragma unroll
    for (int n = 0; n < 4; ++n)
        boff[n] = ((w & 3) * 64 + n * 16 + fr) * 64 + axc;

    f32x4 acc[8][4] = {};

#define STAGE256(S) do {                                                                    \
    const int sb_ = (S) & 3;                                                                \
    __builtin_amdgcn_global_load_lds(AS1(Ag + (size_t)(S) * 32 + ga),                       \
        AS3((char*)&Asl[sb_][0] + tid * 16), 16, 0, 0);                                     \
    __builtin_amdgcn_global_load_lds(AS1(Ag + (size_t)(S) * 32 + ga2),                      \
        AS3((char*)&Asl[sb_][0] + tid * 16 + 8192), 16, 0, 0);                              \
    __builtin_amdgcn_global_load_lds(AS1(Bg + (size_t)(S) * 32 + ga),                       \
        AS3((char*)&Bsl[sb_][0] + tid * 16), 16, 0, 0);                                     \
    __builtin_amdgcn_global_load_lds(AS1(Bg + (size_t)(S) * 32 + ga2),                      \
        AS3((char*)&Bsl[sb_][0] + tid * 16 + 8192), 16, 0, 0);                              \
} while (0)

#define PHASE256(S, VMSTR, DOSTAGE) do {                                                    \
    asm volatile("s_waitcnt vmcnt(" VMSTR ")" ::: "memory");                                \
    __builtin_amdgcn_s_barrier();                                                           \
    __builtin_amdgcn_sched_barrier(0);                                                      \
    const int pb_ = (S) & 3;                                                                \
    bf16x8 af[8], bfv[4];                                                                   \
    _Pragma("unroll")                                                                       \
    for (int m = 0; m < 8; ++m)                                                             \
        af[m] = *(const bf16x8*)((const char*)&Asl[pb_][0] + aoff[m]);                      \
    _Pragma("unroll")                                                                       \
    for (int n = 0; n < 4; ++n)                                                             \
        bfv[n] = *(const bf16x8*)((const char*)&Bsl[pb_][0] + boff[n]);                     \
    if (DOSTAGE) STAGE256((S) + 3);                                                         \
    __builtin_amdgcn_s_setprio(1);                                                          \
    _Pragma("unroll")                                                                       \
    for (int m = 0; m < 8; ++m)                                                             \
        _Pragma("unroll")                                                                   \
        for (int n = 0; n < 4; ++n)                                                         \
            acc[m][n] = __builtin_amdgcn_mfma_f32_16x16x32_bf16(af[m], bfv[n], acc[m][n], 0, 0, 0); \
    __builtin_amdgcn_s_setprio(0);                                                          \
} while (0)

    const int S = K >> 5;
    STAGE256(0); STAGE256(1); STAGE256(2);
    for (int s = 0; s < S - 2; ++s)
        PHASE256(s, "8", (s + 3 < S));
    PHASE256(S - 2, "4", false);
    PHASE256(S - 1, "0", false);
#undef PHASE256
#undef STAGE256

    // ---------------- epilogue: C/D layout col = fr, row = fk*4 + r
    const int rb0 = bm * 256 + (w >> 2) * 128 + fk * 4;
    const int cb0 = bn * 256 + (w & 3) * 64;

    if (MODE == 1) {
        #pragma unroll
        for (int m = 0; m < 8; ++m)
            #pragma unroll
            for (int n = 0; n < 4; ++n) {
                const int col = cb0 + n * 16 + fr;
                const float bv = bias[col];
                #pragma unroll
                for (int r = 0; r < 4; ++r)
                    Cf[(size_t)(rb0 + m * 16 + r) * N + col] = acc[m][n][r] + bv;
            }
    } else {
        const int sect = bn >> 2;          // 0=q, 1=k, 2=v (nbn=12)
        float wn[4] = {1.f, 1.f, 1.f, 1.f};
        if (sect < 2) {
            const float* wp = (sect == 0) ? qw : kw;
            #pragma unroll
            for (int n = 0; n < 4; ++n) wn[n] = wp[n * 16 + fr];
        }
        #pragma unroll
        for (int m = 0; m < 8; ++m) {
            if (sect < 2) {
                float sc[4];
                #pragma unroll
                for (int r = 0; r < 4; ++r) {
                    float ps = 0.f;
                    #pragma unroll
                    for (int n = 0; n < 4; ++n) ps += acc[m][n][r] * acc[m][n][r];
                    ps += __shfl_xor(ps, 1); ps += __shfl_xor(ps, 2);
                    ps += __shfl_xor(ps, 4); ps += __shfl_xor(ps, 8);
                    sc[r] = rsqrtf(ps * (1.0f / 64.0f) + 1e-6f);
                    if (sect == 0) sc[r] *= 0.18033688011112042f;   // 0.125 * log2(e)
                }
                #pragma unroll
                for (int n = 0; n < 4; ++n)
                    #pragma unroll
                    for (int r = 0; r < 4; ++r)
                        Cb[(size_t)(rb0 + m * 16 + r) * N + cb0 + n * 16 + fr] =
                            (__bf16)(acc[m][n][r] * sc[r] * wn[n]);
            } else {
                #pragma unroll
                for (int n = 0; n < 4; ++n)
                    #pragma unroll
                    for (int r = 0; r < 4; ++r)
                        Cb[(size_t)(rb0 + m * 16 + r) * N + cb0 + n * 16 + fr] =
                            (__bf16)acc[m][n][r];
            }
        }
    }
}

// ---------------------------------------------------------------- V transpose: vt[b][h][d][n]
__global__ __launch_bounds__(256)
void vtrans_kernel(const __bf16* __restrict__ qkv, __bf16* __restrict__ vt)
{
    __shared__ __bf16 T[64][72];
    const int b = blockIdx.z, h = blockIdx.y, nb = blockIdx.x;
    const int t = threadIdx.x;
    {
        const int nl = t >> 2, q4 = t & 3;
        const __bf16* src = qkv + (size_t)(b * 1024 + nb * 64 + nl) * 3072 + 2048 + h * 64 + q4 * 16;
        bf16x8 v0 = *(const bf16x8*)src;
        bf16x8 v1 = *(const bf16x8*)(src + 8);
        *(bf16x8*)&T[nl][q4 * 16] = v0;
        *(bf16x8*)&T[nl][q4 * 16 + 8] = v1;
    }
    __syncthreads();
    {
        const int dl = t >> 2, nq = t & 3;
        bf16x8 o0, o1;
        #pragma unroll
        for (int i = 0; i < 8; ++i) { o0[i] = T[nq * 16 + i][dl]; o1[i] = T[nq * 16 + 8 + i][dl]; }
        __bf16* dst = vt + ((size_t)((b * 16 + h) * 64 + dl)) * 1024 + nb * 64 + nq * 16;
        *(bf16x8*)dst = o0;
        *(bf16x8*)(dst + 8) = o1;
    }
}

// ---------------------------------------------------------------- flash attention v5
// 2 q-tiles/wave (128 q-rows/block, grid 2048) -> ~148 live regs, fits 3 blocks/CU.
// exp2-space softmax (log2e folded into q), defer-max (THR=11 log2 units).
__global__ __launch_bounds__(256, 3)
void attn_kernel(const __bf16* __restrict__ qkv, const __bf16* __restrict__ vt,
                 __bf16* __restrict__ ao)
{
    __shared__ __bf16 Ks[2][64 * 64];
    __shared__ __bf16 Vs[2][64 * 64];
    __shared__ __bf16 Pl[4][16 * 64];
    const int tid = threadIdx.x, l = tid & 63, w = tid >> 6;
    const int fr = l & 15, fk = l >> 4;
    const int sw = (fr & 7) << 4;

    // XCD-chunked: 2048 blocks / 8 XCDs; qb fastest so blocks sharing (b,h) co-reside
    const int bi = blockIdx.x;
    const int L = (bi & 7) * 256 + (bi >> 3);
    const int qb = L & 7, h = (L >> 3) & 15, b = L >> 7;

    const __bf16* Kg = qkv + (size_t)b * 1024 * 3072 + 1024 + h * 64;
    const __bf16* Vg = vt + (size_t)((b * 16 + h) * 64) * 1024;
    const int srow = tid >> 3, scp = tid & 7;

#define STAGE(KT, BUF) do {                                                               \
    _Pragma("unroll")                                                                     \
    for (int i_ = 0; i_ < 2; ++i_) {                                                      \
        const int row_ = i_ * 32 + srow;                                                  \
        const int c_ = scp ^ (row_ & 7);                                                  \
        __builtin_amdgcn_global_load_lds(AS1(Kg + (size_t)((KT) * 64 + row_) * 3072 + c_ * 8), \
                                         AS3(&Ks[BUF][i_ * 2048 + tid * 8]), 16, 0, 0);   \
        __builtin_amdgcn_global_load_lds(AS1(Vg + (size_t)row_ * 1024 + (KT) * 64 + c_ * 8),   \
                                         AS3(&Vs[BUF][i_ * 2048 + tid * 8]), 16, 0, 0);   \
    } } while (0)

    STAGE(0, 0);

    const int qrow0 = b * 1024 + qb * 128 + w * 32;
    bf16x8 qf[2][2];
    #pragma unroll
    for (int qi = 0; qi < 2; ++qi)
        #pragma unroll
        for (int dc = 0; dc < 2; ++dc)
            qf[qi][dc] = *(const bf16x8*)&qkv[(size_t)(qrow0 + qi * 16 + fr) * 3072
                                              + h * 64 + dc * 32 + fk * 8];

    f32x4 oacc[2][4] = {};
    float m_r[2], ls[2];
    #pragma unroll
    for (int qi = 0; qi < 2; ++qi) { m_r[qi] = -1e30f; ls[qi] = 0.0f; }

    char* Pw = (char*)&Pl[w][0];
    __syncthreads();

    for (int kt = 0; kt < 16; ++kt) {
        const int cur = kt & 1;
        if (kt < 15) STAGE(kt + 1, cur ^ 1);

        bf16x8 kf[4][2], vf[4][2];
        #pragma unroll
        for (int n = 0; n < 4; ++n)
            #pragma unroll
            for (int dc = 0; dc < 2; ++dc)
                kf[n][dc] = *(const bf16x8*)&Ks[cur][(n * 16 + fr) * 64
                                                     + (((dc * 4 + fk) ^ (fr & 7)) * 8)];
        #pragma unroll
        for (int nd = 0; nd < 4; ++nd)
            #pragma unroll
            for (int kc = 0; kc < 2; ++kc)
                vf[nd][kc] = *(const bf16x8*)&Vs[cur][(nd * 16 + fr) * 64
                                                      + (((kc * 4 + fk) ^ (fr & 7)) * 8)];

        #pragma unroll
        for (int qi = 0; qi < 2; ++qi) {
            f32x4 sacc[4] = {};
            #pragma unroll
            for (int n = 0; n < 4; ++n)
                #pragma unroll
                for (int dc = 0; dc < 2; ++dc)
                    sacc[n] = __builtin_amdgcn_mfma_f32_16x16x32_bf16(kf[n][dc], qf[qi][dc],
                                                                      sacc[n], 0, 0, 0);

            float tm = -1e30f;
            #pragma unroll
            for (int n = 0; n < 4; ++n)
                #pragma unroll
                for (int r = 0; r < 4; ++r)
                    tm = fmaxf(tm, sacc[n][r]);
            tm = fmaxf(tm, __shfl_xor(tm, 16));
            tm = fmaxf(tm, __shfl_xor(tm, 32));

            // defer-max: rescale only when the running max grew by > 11 (log2 units)
            if (__any(tm > m_r[qi] + 11.0f)) {
                const float mnew = fmaxf(m_r[qi], tm);
                const float resc = exp2f(m_r[qi] - mnew);
                m_r[qi] = mnew;
                ls[qi] *= resc;
                float rb[4];
                #pragma unroll
                for (int r = 0; r < 4; ++r) rb[r] = __shfl(resc, (l & 48) + fk * 4 + r);
                #pragma unroll
                for (int nd = 0; nd < 4; ++nd)
                    #pragma unroll
                    for (int r = 0; r < 4; ++r) oacc[qi][nd][r] *= rb[r];
            }

            const float mcur = m_r[qi];
            float psum = 0.0f;
            #pragma unroll
            for (int n = 0; n < 4; ++n) {
                bf16x4 pk;
                #pragma unroll
                for (int r = 0; r < 4; ++r) {
                    float p = exp2f(sacc[n][r] - mcur);
                    psum += p;
                    pk[r] = (__bf16)p;
                }
                *(bf16x4*)(Pw + ((fr * 128 + n * 32 + fk * 8) ^ sw)) = pk;
            }
            psum += __shfl_xor(psum, 16);
            psum += __shfl_xor(psum, 32);
            ls[qi] += psum;

            bf16x8 pf[2];
            #pragma unroll
            for (int kc = 0; kc < 2; ++kc)
                pf[kc] = *(const bf16x8*)(Pw + ((fr * 128 + kc * 64 + fk * 16) ^ sw));
            #pragma unroll
            for (int nd = 0; nd < 4; ++nd)
                #pragma unroll
                for (int kc = 0; kc < 2; ++kc)
                    oacc[qi][nd] = __builtin_amdgcn_mfma_f32_16x16x32_bf16(pf[kc], vf[nd][kc],
                                                                           oacc[qi][nd], 0, 0, 0);
        }
        __syncthreads();
    }

    #pragma unroll
    for (int qi = 0; qi < 2; ++qi) {
        float inv[4];
        #pragma unroll
        for (int r = 0; r < 4; ++r)
            inv[r] = __builtin_amdgcn_rcpf(__shfl(ls[qi], (l & 48) + fk * 4 + r));
        #pragma unroll
        for (int nd = 0; nd < 4; ++nd)
            #pragma unroll
            for (int r = 0; r < 4; ++r)
                ao[(size_t)(qrow0 + qi * 16 + fk * 4 + r) * 1024 + h * 64 + nd * 16 + fr] =
                    (__bf16)(oacc[qi][nd][r] * inv[r]);
    }
#undef STAGE
}

// ---------------------------------------------------------------- launch
extern "C" void kernel_launch(void* const* d_in, const int* in_sizes, int n_in,
                              void* d_out, int out_size, void* d_ws, size_t ws_size,
                              hipStream_t stream)
{
    const float* x      = (const float*)d_in[0];
    const float* qkv_w  = (const float*)d_in[1];
    const float* proj_w = (const float*)d_in[2];
    const float* proj_b = (const float*)d_in[3];
    const float* qnw    = (const float*)d_in[4];
    const float* knw    = (const float*)d_in[5];

    char* ws = (char*)d_ws;
    __bf16* xb    = (__bf16*)(ws);                                 // 32 MB (reused as vt later)
    __bf16* wqkv  = (__bf16*)(ws + 33554432);                      // 6 MB
    __bf16* wproj = (__bf16*)(ws + 33554432 + 6291456);            // 2 MB
    __bf16* qkv   = (__bf16*)(ws + 41943040);                      // 96 MB
    __bf16* ao    = (__bf16*)(ws + 41943040 + 100663296);          // 32 MB
    __bf16* vt    = xb;                                            // xb dead after QKV GEMM

    f2b_kernel<<<2048, 256, 0, stream>>>((const float4*)x,      (bf16x4*)xb,    16777216 / 4);
    f2b_kernel<<<2048, 256, 0, stream>>>((const float4*)qkv_w,  (bf16x4*)wqkv,  3145728 / 4);
    f2b_kernel<<<1024, 256, 0, stream>>>((const float4*)proj_w, (bf16x4*)wproj, 1048576 / 4);

    gemm256<0><<<768, 512, 0, stream>>>(xb, wqkv, nullptr, qnw, knw,
                                        nullptr, qkv, 16384, 3072, 1024, 12);
    vtrans_kernel<<<dim3(16, 16, 16), 256, 0, stream>>>(qkv, vt);
    attn_kernel<<<2048, 256, 0, stream>>>(qkv, vt, ao);
    gemm256<1><<<256, 512, 0, stream>>>(ao, wproj, proj_b, nullptr, nullptr,
                                        (float*)d_out, nullptr, 16384, 1024, 1024, 4);
}

// Round 8
// 292.194 us; speedup vs baseline: 3.1067x; 1.0575x over previous
//
#include <hip/hip_runtime.h>
#include <hip/hip_bf16.h>

typedef __attribute__((ext_vector_type(8))) __bf16 bf16x8;
typedef __attribute__((ext_vector_type(4))) __bf16 bf16x4;
typedef __attribute__((ext_vector_type(4))) float f32x4;

#define AS1(p) ((__attribute__((address_space(1))) void*)(p))
#define AS3(p) ((__attribute__((address_space(3))) void*)(p))

// ---------------------------------------------------------------- f32 -> bf16
__global__ void f2b_kernel(const float4* __restrict__ in, bf16x4* __restrict__ out, int n4) {
    int idx = blockIdx.x * blockDim.x + threadIdx.x;
    int stride = gridDim.x * blockDim.x;
    for (int i = idx; i < n4; i += stride) {
        float4 v = in[i];
        bf16x4 o;
        o[0] = (__bf16)v.x; o[1] = (__bf16)v.y; o[2] = (__bf16)v.z; o[3] = (__bf16)v.w;
        out[i] = o;
    }
}

// ---------------------------------------------------------------- 256x256 pipelined GEMM
// C = A @ B^T. 512 thr = 8 waves (2M x 4N), per-wave 128x64 output, acc[8][4].
// K in 32-wide slots; 4-slot LDS ring staged 3 ahead (counted vmcnt, 1 barrier/slot).
// MODE 0: qkv. q,k -> Cb[row][ldc=2048] with fused per-head RMSNorm
//         (q scaled by Dh^-0.5 * log2e); v -> transposed into Vt[b][h][d][n].
// MODE 1: f32 out + bias, ldc = N.
template<int MODE>
__global__ __launch_bounds__(512, 2)
void gemm256(const __bf16* __restrict__ A, const __bf16* __restrict__ Bw,
             const float* __restrict__ bias, const float* __restrict__ qw,
             const float* __restrict__ kw, float* __restrict__ Cf,
             __bf16* __restrict__ Cb, __bf16* __restrict__ Vt,
             int M, int K, int nbn, int ldc)
{
    __shared__ __bf16 Asl[4][256 * 32];
    __shared__ __bf16 Bsl[4][256 * 32];
    const int tid = threadIdx.x, l = tid & 63, w = tid >> 6;
    const int fr = l & 15, fk = l >> 4;

    const int cpx = gridDim.x >> 3;
    const int wg = (blockIdx.x & 7) * cpx + (blockIdx.x >> 3);
    const int bm = wg / nbn, bn = wg % nbn;

    const __bf16* Ag = A + (size_t)bm * 256 * K;
    const __bf16* Bg = Bw + (size_t)bn * 256 * K;

    const int arow = tid >> 2;
    const int uch = (tid & 3) ^ (arow & 3);
    const size_t ga = (size_t)arow * K + uch * 8;
    const size_t ga2 = ga + (size_t)128 * K;

    const int axc = (fk ^ (fr & 3)) * 16;
    int aoff[8], boff[4];
    #pragma unroll
    for (int m = 0; m < 8; ++m)
        aoff[m] = ((w >> 2) * 128 + m * 16 + fr) * 64 + axc;
    #pragma unroll
    for (int n = 0; n < 4; ++n)
        boff[n] = ((w & 3) * 64 + n * 16 + fr) * 64 + axc;

    f32x4 acc[8][4] = {};

#define STAGE256(S) do {                                                                    \
    const int sb_ = (S) & 3;                                                                \
    __builtin_amdgcn_global_load_lds(AS1(Ag + (size_t)(S) * 32 + ga),                       \
        AS3((char*)&Asl[sb_][0] + tid * 16), 16, 0, 0);                                     \
    __builtin_amdgcn_global_load_lds(AS1(Ag + (size_t)(S) * 32 + ga2),                      \
        AS3((char*)&Asl[sb_][0] + tid * 16 + 8192), 16, 0, 0);                              \
    __builtin_amdgcn_global_load_lds(AS1(Bg + (size_t)(S) * 32 + ga),                       \
        AS3((char*)&Bsl[sb_][0] + tid * 16), 16, 0, 0);                                     \
    __builtin_amdgcn_global_load_lds(AS1(Bg + (size_t)(S) * 32 + ga2),                      \
        AS3((char*)&Bsl[sb_][0] + tid * 16 + 8192), 16, 0, 0);                              \
} while (0)

#define PHASE256(S, VMSTR, DOSTAGE) do {                                                    \
    asm volatile("s_waitcnt vmcnt(" VMSTR ")" ::: "memory");                                \
    __builtin_amdgcn_s_barrier();                                                           \
    __builtin_amdgcn_sched_barrier(0);                                                      \
    const int pb_ = (S) & 3;                                                                \
    bf16x8 af[8], bfv[4];                                                                   \
    _Pragma("unroll")                                                                       \
    for (int m = 0; m < 8; ++m)                                                             \
        af[m] = *(const bf16x8*)((const char*)&Asl[pb_][0] + aoff[m]);                      \
    _Pragma("unroll")                                                                       \
    for (int n = 0; n < 4; ++n)                                                             \
        bfv[n] = *(const bf16x8*)((const char*)&Bsl[pb_][0] + boff[n]);                     \
    if (DOSTAGE) STAGE256((S) + 3);                                                         \
    __builtin_amdgcn_s_setprio(1);                                                          \
    _Pragma("unroll")                                                                       \
    for (int m = 0; m < 8; ++m)                                                             \
        _Pragma("unroll")                                                                   \
        for (int n = 0; n < 4; ++n)                                                         \
            acc[m][n] = __builtin_amdgcn_mfma_f32_16x16x32_bf16(af[m], bfv[n], acc[m][n], 0, 0, 0); \
    __builtin_amdgcn_s_setprio(0);                                                          \
} while (0)

    const int S = K >> 5;
    STAGE256(0); STAGE256(1); STAGE256(2);
    for (int s = 0; s < S - 2; ++s)
        PHASE256(s, "8", (s + 3 < S));
    PHASE256(S - 2, "4", false);
    PHASE256(S - 1, "0", false);
#undef PHASE256
#undef STAGE256

    // ---------------- epilogue: C/D layout col = fr, row = fk*4 + r
    const int rb0 = bm * 256 + (w >> 2) * 128 + fk * 4;
    const int cb0 = bn * 256 + (w & 3) * 64;

    if (MODE == 1) {
        #pragma unroll
        for (int m = 0; m < 8; ++m)
            #pragma unroll
            for (int n = 0; n < 4; ++n) {
                const int col = cb0 + n * 16 + fr;
                const float bv = bias[col];
                #pragma unroll
                for (int r = 0; r < 4; ++r)
                    Cf[(size_t)(rb0 + m * 16 + r) * ldc + col] = acc[m][n][r] + bv;
            }
    } else {
        const int sect = bn >> 2;          // 0=q, 1=k, 2=v (nbn=12)
        if (sect < 2) {
            const float* wp = (sect == 0) ? qw : kw;
            float wn[4];
            #pragma unroll
            for (int n = 0; n < 4; ++n) wn[n] = wp[((w & 3) * 64 + n * 16 + fr) & 63];
            #pragma unroll
            for (int m = 0; m < 8; ++m) {
                float sc[4];
                #pragma unroll
                for (int r = 0; r < 4; ++r) {
                    float ps = 0.f;
                    #pragma unroll
                    for (int n = 0; n < 4; ++n) ps += acc[m][n][r] * acc[m][n][r];
                    ps += __shfl_xor(ps, 1); ps += __shfl_xor(ps, 2);
                    ps += __shfl_xor(ps, 4); ps += __shfl_xor(ps, 8);
                    sc[r] = rsqrtf(ps * (1.0f / 64.0f) + 1e-6f);
                    if (sect == 0) sc[r] *= 0.18033688011112042f;   // 0.125 * log2(e)
                }
                #pragma unroll
                for (int n = 0; n < 4; ++n)
                    #pragma unroll
                    for (int r = 0; r < 4; ++r)
                        Cb[(size_t)(rb0 + m * 16 + r) * ldc + cb0 + n * 16 + fr] =
                            (__bf16)(acc[m][n][r] * sc[r] * wn[n]);
            }
        } else {
            // v -> Vt[((b*16+h)*64+d)*1024 + token], token-contiguous 8B stores
            #pragma unroll
            for (int m = 0; m < 8; ++m) {
                const int tok = rb0 + m * 16;          // +r contiguous, same 1024-block
                const int b = tok >> 10, ntok = tok & 1023;
                #pragma unroll
                for (int n = 0; n < 4; ++n) {
                    const int vd = (bn - 8) * 256 + (w & 3) * 64 + n * 16 + fr; // [0,1024)
                    bf16x4 pk;
                    #pragma unroll
                    for (int r = 0; r < 4; ++r) pk[r] = (__bf16)acc[m][n][r];
                    *(bf16x4*)&Vt[((size_t)((b * 16 + (vd >> 6)) * 64 + (vd & 63))) * 1024 + ntok] = pk;
                }
            }
        }
    }
}

// ---------------------------------------------------------------- flash attention v6
// 2 q-tiles/wave (128 q-rows/block, grid 2048), 3 blocks/CU.
// No-max softmax: scores bounded (|q̂||k̂| <= 11.6 log2 units after RMSNorm),
// p = exp2(s) directly; lane-partial ls reduced once in epilogue.
__global__ __launch_bounds__(256, 3)
void attn_kernel(const __bf16* __restrict__ qkv, const __bf16* __restrict__ vt,
                 __bf16* __restrict__ ao)
{
    __shared__ __bf16 Ks[2][64 * 64];
    __shared__ __bf16 Vs[2][64 * 64];
    __shared__ __bf16 Pl[4][16 * 64];
    const int tid = threadIdx.x, l = tid & 63, w = tid >> 6;
    const int fr = l & 15, fk = l >> 4;
    const int sw = (fr & 7) << 4;

    // XCD-chunked: 2048 blocks / 8 XCDs; qb fastest so blocks sharing (b,h) co-reside
    const int bi = blockIdx.x;
    const int L = (bi & 7) * 256 + (bi >> 3);
    const int qb = L & 7, h = (L >> 3) & 15, b = L >> 7;

    const __bf16* Kg = qkv + (size_t)b * 1024 * 2048 + 1024 + h * 64;
    const __bf16* Vg = vt + (size_t)((b * 16 + h) * 64) * 1024;
    const int srow = tid >> 3, scp = tid & 7;

#define STAGE(KT, BUF) do {                                                               \
    _Pragma("unroll")                                                                     \
    for (int i_ = 0; i_ < 2; ++i_) {                                                      \
        const int row_ = i_ * 32 + srow;                                                  \
        const int c_ = scp ^ (row_ & 7);                                                  \
        __builtin_amdgcn_global_load_lds(AS1(Kg + (size_t)((KT) * 64 + row_) * 2048 + c_ * 8), \
                                         AS3(&Ks[BUF][i_ * 2048 + tid * 8]), 16, 0, 0);   \
        __builtin_amdgcn_global_load_lds(AS1(Vg + (size_t)row_ * 1024 + (KT) * 64 + c_ * 8),   \
                                         AS3(&Vs[BUF][i_ * 2048 + tid * 8]), 16, 0, 0);   \
    } } while (0)

    STAGE(0, 0);

    const int qrow0 = b * 1024 + qb * 128 + w * 32;
    bf16x8 qf[2][2];
    #pragma unroll
    for (int qi = 0; qi < 2; ++qi)
        #pragma unroll
        for (int dc = 0; dc < 2; ++dc)
            qf[qi][dc] = *(const bf16x8*)&qkv[(size_t)(qrow0 + qi * 16 + fr) * 2048
                                              + h * 64 + dc * 32 + fk * 8];

    f32x4 oacc[2][4] = {};
    float lsp[2] = {0.0f, 0.0f};

    char* Pw = (char*)&Pl[w][0];
    __syncthreads();

    for (int kt = 0; kt < 16; ++kt) {
        const int cur = kt & 1;
        if (kt < 15) STAGE(kt + 1, cur ^ 1);

        bf16x8 kf[4][2], vf[4][2];
        #pragma unroll
        for (int n = 0; n < 4; ++n)
            #pragma unroll
            for (int dc = 0; dc < 2; ++dc)
                kf[n][dc] = *(const bf16x8*)&Ks[cur][(n * 16 + fr) * 64
                                                     + (((dc * 4 + fk) ^ (fr & 7)) * 8)];
        #pragma unroll
        for (int nd = 0; nd < 4; ++nd)
            #pragma unroll
            for (int kc = 0; kc < 2; ++kc)
                vf[nd][kc] = *(const bf16x8*)&Vs[cur][(nd * 16 + fr) * 64
                                                      + (((kc * 4 + fk) ^ (fr & 7)) * 8)];

        #pragma unroll
        for (int qi = 0; qi < 2; ++qi) {
            f32x4 sacc[4] = {};
            #pragma unroll
            for (int n = 0; n < 4; ++n)
                #pragma unroll
                for (int dc = 0; dc < 2; ++dc)
                    sacc[n] = __builtin_amdgcn_mfma_f32_16x16x32_bf16(kf[n][dc], qf[qi][dc],
                                                                      sacc[n], 0, 0, 0);

            // p = exp2(s) directly; scores bounded by ~11.6 -> p <= ~3100, f32-safe
            #pragma unroll
            for (int n = 0; n < 4; ++n) {
                bf16x4 pk;
                #pragma unroll
                for (int r = 0; r < 4; ++r) {
                    float p = exp2f(sacc[n][r]);
                    lsp[qi] += p;
                    pk[r] = (__bf16)p;
                }
                *(bf16x4*)(Pw + ((fr * 128 + n * 32 + fk * 8) ^ sw)) = pk;
            }

            bf16x8 pf[2];
            #pragma unroll
            for (int kc = 0; kc < 2; ++kc)
                pf[kc] = *(const bf16x8*)(Pw + ((fr * 128 + kc * 64 + fk * 16) ^ sw));
            #pragma unroll
            for (int nd = 0; nd < 4; ++nd)
                #pragma unroll
                for (int kc = 0; kc < 2; ++kc)
                    oacc[qi][nd] = __builtin_amdgcn_mfma_f32_16x16x32_bf16(pf[kc], vf[nd][kc],
                                                                           oacc[qi][nd], 0, 0, 0);
        }
        __syncthreads();
    }

    #pragma unroll
    for (int qi = 0; qi < 2; ++qi) {
        float ls = lsp[qi];
        ls += __shfl_xor(ls, 16);
        ls += __shfl_xor(ls, 32);
        float inv[4];
        #pragma unroll
        for (int r = 0; r < 4; ++r)
            inv[r] = __builtin_amdgcn_rcpf(__shfl(ls, (l & 48) + fk * 4 + r));
        #pragma unroll
        for (int nd = 0; nd < 4; ++nd)
            #pragma unroll
            for (int r = 0; r < 4; ++r)
                ao[(size_t)(qrow0 + qi * 16 + fk * 4 + r) * 1024 + h * 64 + nd * 16 + fr] =
                    (__bf16)(oacc[qi][nd][r] * inv[r]);
    }
#undef STAGE
}

// ---------------------------------------------------------------- launch
extern "C" void kernel_launch(void* const* d_in, const int* in_sizes, int n_in,
                              void* d_out, int out_size, void* d_ws, size_t ws_size,
                              hipStream_t stream)
{
    const float* x      = (const float*)d_in[0];
    const float* qkv_w  = (const float*)d_in[1];
    const float* proj_w = (const float*)d_in[2];
    const float* proj_b = (const float*)d_in[3];
    const float* qnw    = (const float*)d_in[4];
    const float* knw    = (const float*)d_in[5];

    char* ws = (char*)d_ws;
    __bf16* xb    = (__bf16*)(ws);                      // 32 MB
    __bf16* wqkv  = (__bf16*)(ws + 33554432);           // 6 MB
    __bf16* wproj = (__bf16*)(ws + 39845888);           // 2 MB
    __bf16* qkv   = (__bf16*)(ws + 41943040);           // 64 MB  [16384][2048] q,k only
    __bf16* vt    = (__bf16*)(ws + 109051904);          // 32 MB  [b][h][d][n]
    __bf16* ao    = (__bf16*)(ws + 142606336);          // 32 MB

    f2b_kernel<<<2048, 256, 0, stream>>>((const float4*)x,      (bf16x4*)xb,    16777216 / 4);
    f2b_kernel<<<2048, 256, 0, stream>>>((const float4*)qkv_w,  (bf16x4*)wqkv,  3145728 / 4);
    f2b_kernel<<<1024, 256, 0, stream>>>((const float4*)proj_w, (bf16x4*)wproj, 1048576 / 4);

    gemm256<0><<<768, 512, 0, stream>>>(xb, wqkv, nullptr, qnw, knw,
                                        nullptr, qkv, vt, 16384, 1024, 12, 2048);
    attn_kernel<<<2048, 256, 0, stream>>>(qkv, vt, ao);
    gemm256<1><<<256, 512, 0, stream>>>(ao, wproj, proj_b, nullptr, nullptr,
                                        (float*)d_out, nullptr, nullptr, 16384, 1024, 4, 1024);
}

// Round 9
// 268.702 us; speedup vs baseline: 3.3783x; 1.0874x over previous
//
#include <hip/hip_runtime.h>
#include <hip/hip_bf16.h>

typedef __attribute__((ext_vector_type(8))) __bf16 bf16x8;
typedef __attribute__((ext_vector_type(4))) __bf16 bf16x4;
typedef __attribute__((ext_vector_type(4))) float f32x4;

#define AS1(p) ((__attribute__((address_space(1))) void*)(p))
#define AS3(p) ((__attribute__((address_space(3))) void*)(p))

// ---------------------------------------------------------------- f32 -> bf16
__global__ void f2b_kernel(const float4* __restrict__ in, bf16x4* __restrict__ out, int n4) {
    int idx = blockIdx.x * blockDim.x + threadIdx.x;
    int stride = gridDim.x * blockDim.x;
    for (int i = idx; i < n4; i += stride) {
        float4 v = in[i];
        bf16x4 o;
        o[0] = (__bf16)v.x; o[1] = (__bf16)v.y; o[2] = (__bf16)v.z; o[3] = (__bf16)v.w;
        out[i] = o;
    }
}

// ---------------------------------------------------------------- 256x256 pipelined GEMM
// C = A @ B^T. 512 thr = 8 waves (2M x 4N), per-wave 128x64 output, acc[8][4].
// K in 32-wide slots; 4-slot LDS ring staged 3 ahead (counted vmcnt, 1 barrier/slot).
// MODE 0: qkv. q,k -> Cb[row][ldc=2048] with fused per-head RMSNorm
//         (q scaled by Dh^-0.5 * log2e); v -> transposed into Vt[b][h][d][n].
// MODE 1: f32 out + bias, ldc = N.
template<int MODE>
__global__ __launch_bounds__(512, 2)
void gemm256(const __bf16* __restrict__ A, const __bf16* __restrict__ Bw,
             const float* __restrict__ bias, const float* __restrict__ qw,
             const float* __restrict__ kw, float* __restrict__ Cf,
             __bf16* __restrict__ Cb, __bf16* __restrict__ Vt,
             int M, int K, int nbn, int ldc)
{
    __shared__ __bf16 Asl[4][256 * 32];
    __shared__ __bf16 Bsl[4][256 * 32];
    const int tid = threadIdx.x, l = tid & 63, w = tid >> 6;
    const int fr = l & 15, fk = l >> 4;

    const int cpx = gridDim.x >> 3;
    const int wg = (blockIdx.x & 7) * cpx + (blockIdx.x >> 3);
    const int bm = wg / nbn, bn = wg % nbn;

    const __bf16* Ag = A + (size_t)bm * 256 * K;
    const __bf16* Bg = Bw + (size_t)bn * 256 * K;

    const int arow = tid >> 2;
    const int uch = (tid & 3) ^ (arow & 3);
    const size_t ga = (size_t)arow * K + uch * 8;
    const size_t ga2 = ga + (size_t)128 * K;

    const int axc = (fk ^ (fr & 3)) * 16;
    int aoff[8], boff[4];
    #pragma unroll
    for (int m = 0; m < 8; ++m)
        aoff[m] = ((w >> 2) * 128 + m * 16 + fr) * 64 + axc;
    #pragma unroll
    for (int n = 0; n < 4; ++n)
        boff[n] = ((w & 3) * 64 + n * 16 + fr) * 64 + axc;

    f32x4 acc[8][4] = {};

#define STAGE256(S) do {                                                                    \
    const int sb_ = (S) & 3;                                                                \
    __builtin_amdgcn_global_load_lds(AS1(Ag + (size_t)(S) * 32 + ga),                       \
        AS3((char*)&Asl[sb_][0] + tid * 16), 16, 0, 0);                                     \
    __builtin_amdgcn_global_load_lds(AS1(Ag + (size_t)(S) * 32 + ga2),                      \
        AS3((char*)&Asl[sb_][0] + tid * 16 + 8192), 16, 0, 0);                              \
    __builtin_amdgcn_global_load_lds(AS1(Bg + (size_t)(S) * 32 + ga),                       \
        AS3((char*)&Bsl[sb_][0] + tid * 16), 16, 0, 0);                                     \
    __builtin_amdgcn_global_load_lds(AS1(Bg + (size_t)(S) * 32 + ga2),                      \
        AS3((char*)&Bsl[sb_][0] + tid * 16 + 8192), 16, 0, 0);                              \
} while (0)

#define PHASE256(S, VMSTR, DOSTAGE) do {                                                    \
    asm volatile("s_waitcnt vmcnt(" VMSTR ")" ::: "memory");                                \
    __builtin_amdgcn_s_barrier();                                                           \
    __builtin_amdgcn_sched_barrier(0);                                                      \
    const int pb_ = (S) & 3;                                                                \
    bf16x8 af[8], bfv[4];                                                                   \
    _Pragma("unroll")                                                                       \
    for (int m = 0; m < 8; ++m)                                                             \
        af[m] = *(const bf16x8*)((const char*)&Asl[pb_][0] + aoff[m]);                      \
    _Pragma("unroll")                                                                       \
    for (int n = 0; n < 4; ++n)                                                             \
        bfv[n] = *(const bf16x8*)((const char*)&Bsl[pb_][0] + boff[n]);                     \
    if (DOSTAGE) STAGE256((S) + 3);                                                         \
    __builtin_amdgcn_s_setprio(1);                                                          \
    _Pragma("unroll")                                                                       \
    for (int m = 0; m < 8; ++m)                                                             \
        _Pragma("unroll")                                                                   \
        for (int n = 0; n < 4; ++n)                                                         \
            acc[m][n] = __builtin_amdgcn_mfma_f32_16x16x32_bf16(af[m], bfv[n], acc[m][n], 0, 0, 0); \
    __builtin_amdgcn_s_setprio(0);                                                          \
} while (0)

    const int S = K >> 5;
    STAGE256(0); STAGE256(1); STAGE256(2);
    for (int s = 0; s < S - 2; ++s)
        PHASE256(s, "8", (s + 3 < S));
    PHASE256(S - 2, "4", false);
    PHASE256(S - 1, "0", false);
#undef PHASE256
#undef STAGE256

    // ---------------- epilogue: C/D layout col = fr, row = fk*4 + r
    const int rb0 = bm * 256 + (w >> 2) * 128 + fk * 4;
    const int cb0 = bn * 256 + (w & 3) * 64;

    if (MODE == 1) {
        #pragma unroll
        for (int m = 0; m < 8; ++m)
            #pragma unroll
            for (int n = 0; n < 4; ++n) {
                const int col = cb0 + n * 16 + fr;
                const float bv = bias[col];
                #pragma unroll
                for (int r = 0; r < 4; ++r)
                    Cf[(size_t)(rb0 + m * 16 + r) * ldc + col] = acc[m][n][r] + bv;
            }
    } else {
        const int sect = bn >> 2;          // 0=q, 1=k, 2=v (nbn=12)
        if (sect < 2) {
            const float* wp = (sect == 0) ? qw : kw;
            float wn[4];
            #pragma unroll
            for (int n = 0; n < 4; ++n) wn[n] = wp[((w & 3) * 64 + n * 16 + fr) & 63];
            #pragma unroll
            for (int m = 0; m < 8; ++m) {
                float sc[4];
                #pragma unroll
                for (int r = 0; r < 4; ++r) {
                    float ps = 0.f;
                    #pragma unroll
                    for (int n = 0; n < 4; ++n) ps += acc[m][n][r] * acc[m][n][r];
                    ps += __shfl_xor(ps, 1); ps += __shfl_xor(ps, 2);
                    ps += __shfl_xor(ps, 4); ps += __shfl_xor(ps, 8);
                    sc[r] = rsqrtf(ps * (1.0f / 64.0f) + 1e-6f);
                    if (sect == 0) sc[r] *= 0.18033688011112042f;   // 0.125 * log2(e)
                }
                #pragma unroll
                for (int n = 0; n < 4; ++n)
                    #pragma unroll
                    for (int r = 0; r < 4; ++r)
                        Cb[(size_t)(rb0 + m * 16 + r) * ldc + cb0 + n * 16 + fr] =
                            (__bf16)(acc[m][n][r] * sc[r] * wn[n]);
            }
        } else {
            // v -> Vt[((b*16+h)*64+d)*1024 + token], token-contiguous 8B stores
            #pragma unroll
            for (int m = 0; m < 8; ++m) {
                const int tok = rb0 + m * 16;          // +r contiguous, same 1024-block
                const int b = tok >> 10, ntok = tok & 1023;
                #pragma unroll
                for (int n = 0; n < 4; ++n) {
                    const int vd = (bn - 8) * 256 + (w & 3) * 64 + n * 16 + fr; // [0,1024)
                    bf16x4 pk;
                    #pragma unroll
                    for (int r = 0; r < 4; ++r) pk[r] = (__bf16)acc[m][n][r];
                    *(bf16x4*)&Vt[((size_t)((b * 16 + (vd >> 6)) * 64 + (vd & 63))) * 1024 + ntok] = pk;
                }
            }
        }
    }
}

// ---------------------------------------------------------------- flash attention v7
// 2 q-tiles/wave (128 q-rows/block, grid 2048), 3 blocks/CU.
// No-max softmax (scores bounded +-11.6 log2 units after RMSNorm): p = v_exp_f32(s).
// ls computed via MFMA against a ones B-fragment (no serial add chain, no shfls).
// All LDS addresses hoisted: frag reads = base + cur*8192 + immediate.
__global__ __launch_bounds__(256, 3)
void attn_kernel(const __bf16* __restrict__ qkv, const __bf16* __restrict__ vt,
                 __bf16* __restrict__ ao)
{
    __shared__ __bf16 Ks[2][64 * 64];
    __shared__ __bf16 Vs[2][64 * 64];
    __shared__ __bf16 Pl[4][16 * 64];
    const int tid = threadIdx.x, l = tid & 63, w = tid >> 6;
    const int fr = l & 15, fk = l >> 4;
    const int sw = (fr & 7) << 4;

    // XCD-chunked: 2048 blocks / 8 XCDs; qb fastest so blocks sharing (b,h) co-reside
    const int bi = blockIdx.x;
    const int L = (bi & 7) * 256 + (bi >> 3);
    const int qb = L & 7, h = (L >> 3) & 15, b = L >> 7;

    const __bf16* Kg = qkv + (size_t)b * 1024 * 2048 + 1024 + h * 64;
    const __bf16* Vg = vt + (size_t)((b * 16 + h) * 64) * 1024;
    const int srow = tid >> 3, scp = tid & 7;

    // hoisted staging offsets ((32+srow)&7 == srow&7, so c8 shared by both halves)
    const int c8 = (scp ^ (srow & 7)) * 8;
    const size_t kO0 = (size_t)srow * 2048 + c8, kO1 = kO0 + 32 * 2048;
    const size_t vO0 = (size_t)srow * 1024 + c8, vO1 = vO0 + 32 * 1024;
    char* ksd = (char*)&Ks[0][0] + tid * 16;
    char* vsd = (char*)&Vs[0][0] + tid * 16;

#define STAGE(KP, VP, BUF) do {                                                           \
    __builtin_amdgcn_global_load_lds(AS1((KP) + kO0), AS3(ksd + (BUF) * 8192), 16, 0, 0); \
    __builtin_amdgcn_global_load_lds(AS1((KP) + kO1), AS3(ksd + (BUF) * 8192 + 4096), 16, 0, 0); \
    __builtin_amdgcn_global_load_lds(AS1((VP) + vO0), AS3(vsd + (BUF) * 8192), 16, 0, 0); \
    __builtin_amdgcn_global_load_lds(AS1((VP) + vO1), AS3(vsd + (BUF) * 8192 + 4096), 16, 0, 0); \
} while (0)

    STAGE(Kg, Vg, 0);

    const int qrow0 = b * 1024 + qb * 128 + w * 32;
    bf16x8 qf[2][2];
    #pragma unroll
    for (int qi = 0; qi < 2; ++qi)
        #pragma unroll
        for (int dc = 0; dc < 2; ++dc)
            qf[qi][dc] = *(const bf16x8*)&qkv[(size_t)(qrow0 + qi * 16 + fr) * 2048
                                              + h * 64 + dc * 32 + fk * 8];

    // hoisted frag-read byte offsets (within one 8KB buffer)
    const int kb0 = fr * 128 + ((fk ^ (fr & 7)) * 16);
    const int kb1 = fr * 128 + (((4 + fk) ^ (fr & 7)) * 16);
    const char* KsB = (const char*)&Ks[0][0];
    const char* VsB = (const char*)&Vs[0][0];

    // hoisted P byte offsets (per-wave 2KB region)
    char* Pw = (char*)&Pl[w][0];
    const int pw0 = (fr * 128 + 0 * 32 + fk * 8) ^ sw;
    const int pw1 = (fr * 128 + 1 * 32 + fk * 8) ^ sw;
    const int pw2 = (fr * 128 + 2 * 32 + fk * 8) ^ sw;
    const int pw3 = (fr * 128 + 3 * 32 + fk * 8) ^ sw;
    const int pr0 = (fr * 128 + 0 * 64 + fk * 16) ^ sw;
    const int pr1 = (fr * 128 + 1 * 64 + fk * 16) ^ sw;

    bf16x8 onesf;
    #pragma unroll
    for (int i = 0; i < 8; ++i) onesf[i] = (__bf16)1.0f;

    f32x4 oacc[2][4] = {};
    f32x4 lacc[2] = {};

    const __bf16* kg = Kg;
    const __bf16* vg = Vg;
    __syncthreads();

    for (int kt = 0; kt < 16; ++kt) {
        const int cur = kt & 1;
        if (kt < 15) { kg += 64 * 2048; vg += 64; STAGE(kg, vg, cur ^ 1); }

        const int cb = cur * 8192;
        bf16x8 kf[4][2], vf[4][2];
        #pragma unroll
        for (int n = 0; n < 4; ++n) {
            kf[n][0] = *(const bf16x8*)(KsB + cb + kb0 + n * 2048);
            kf[n][1] = *(const bf16x8*)(KsB + cb + kb1 + n * 2048);
        }
        #pragma unroll
        for (int nd = 0; nd < 4; ++nd) {
            vf[nd][0] = *(const bf16x8*)(VsB + cb + kb0 + nd * 2048);
            vf[nd][1] = *(const bf16x8*)(VsB + cb + kb1 + nd * 2048);
        }

        #pragma unroll
        for (int qi = 0; qi < 2; ++qi) {
            f32x4 sacc[4] = {};
            #pragma unroll
            for (int n = 0; n < 4; ++n)
                #pragma unroll
                for (int dc = 0; dc < 2; ++dc)
                    sacc[n] = __builtin_amdgcn_mfma_f32_16x16x32_bf16(kf[n][dc], qf[qi][dc],
                                                                      sacc[n], 0, 0, 0);

            // p = exp2(s) directly (raw v_exp_f32); scores bounded -> p <= ~3100
            #pragma unroll
            for (int n = 0; n < 4; ++n) {
                bf16x4 pk;
                #pragma unroll
                for (int r = 0; r < 4; ++r)
                    pk[r] = (__bf16)__builtin_amdgcn_exp2f(sacc[n][r]);
                const int pwn = (n == 0) ? pw0 : (n == 1) ? pw1 : (n == 2) ? pw2 : pw3;
                *(bf16x4*)(Pw + pwn) = pk;
            }

            bf16x8 pf0 = *(const bf16x8*)(Pw + pr0);
            bf16x8 pf1 = *(const bf16x8*)(Pw + pr1);
            // ls row-sums on the MFMA pipe: D[q][*] = sum_k P[q][k]
            lacc[qi] = __builtin_amdgcn_mfma_f32_16x16x32_bf16(pf0, onesf, lacc[qi], 0, 0, 0);
            lacc[qi] = __builtin_amdgcn_mfma_f32_16x16x32_bf16(pf1, onesf, lacc[qi], 0, 0, 0);
            #pragma unroll
            for (int nd = 0; nd < 4; ++nd) {
                oacc[qi][nd] = __builtin_amdgcn_mfma_f32_16x16x32_bf16(pf0, vf[nd][0],
                                                                       oacc[qi][nd], 0, 0, 0);
                oacc[qi][nd] = __builtin_amdgcn_mfma_f32_16x16x32_bf16(pf1, vf[nd][1],
                                                                       oacc[qi][nd], 0, 0, 0);
            }
        }
        __syncthreads();
    }

    // epilogue: lacc[qi][r] is ls for row fk*4+r (same mapping as oacc rows)
    #pragma unroll
    for (int qi = 0; qi < 2; ++qi) {
        float inv[4];
        #pragma unroll
        for (int r = 0; r < 4; ++r)
            inv[r] = __builtin_amdgcn_rcpf(lacc[qi][r]);
        #pragma unroll
        for (int nd = 0; nd < 4; ++nd)
            #pragma unroll
            for (int r = 0; r < 4; ++r)
                ao[(size_t)(qrow0 + qi * 16 + fk * 4 + r) * 1024 + h * 64 + nd * 16 + fr] =
                    (__bf16)(oacc[qi][nd][r] * inv[r]);
    }
#undef STAGE
}

// ---------------------------------------------------------------- launch
extern "C" void kernel_launch(void* const* d_in, const int* in_sizes, int n_in,
                              void* d_out, int out_size, void* d_ws, size_t ws_size,
                              hipStream_t stream)
{
    const float* x      = (const float*)d_in[0];
    const float* qkv_w  = (const float*)d_in[1];
    const float* proj_w = (const float*)d_in[2];
    const float* proj_b = (const float*)d_in[3];
    const float* qnw    = (const float*)d_in[4];
    const float* knw    = (const float*)d_in[5];

    char* ws = (char*)d_ws;
    __bf16* xb    = (__bf16*)(ws);                      // 32 MB
    __bf16* wqkv  = (__bf16*)(ws + 33554432);           // 6 MB
    __bf16* wproj = (__bf16*)(ws + 39845888);           // 2 MB
    __bf16* qkv   = (__bf16*)(ws + 41943040);           // 64 MB  [16384][2048] q,k only
    __bf16* vt    = (__bf16*)(ws + 109051904);          // 32 MB  [b][h][d][n]
    __bf16* ao    = (__bf16*)(ws + 142606336);          // 32 MB

    f2b_kernel<<<2048, 256, 0, stream>>>((const float4*)x,      (bf16x4*)xb,    16777216 / 4);
    f2b_kernel<<<2048, 256, 0, stream>>>((const float4*)qkv_w,  (bf16x4*)wqkv,  3145728 / 4);
    f2b_kernel<<<1024, 256, 0, stream>>>((const float4*)proj_w, (bf16x4*)wproj, 1048576 / 4);

    gemm256<0><<<768, 512, 0, stream>>>(xb, wqkv, nullptr, qnw, knw,
                                        nullptr, qkv, vt, 16384, 1024, 12, 2048);
    attn_kernel<<<2048, 256, 0, stream>>>(qkv, vt, ao);
    gemm256<1><<<256, 512, 0, stream>>>(ao, wproj, proj_b, nullptr, nullptr,
                                        (float*)d_out, nullptr, nullptr, 16384, 1024, 4, 1024);
}